// Round 4
// baseline (134.481 us; speedup 1.0000x reference)
//
#include <hip/hip_runtime.h>
#include <hip/hip_bf16.h>

// deepSNN forward, layer_idx=3 path. fp32 x, bf16 MFMA conv1 AND conv2.
// x:(20,6,160,160) w1:(30,6,4,4) w2:(250,30,3,3) w3:(200,250,3,3)
// pipeline: pad2->conv1->fire(1)->pool2x2 -> pad2->conv2->fire(1)->pool3x3
//           -> pad2->conv3->fire(25) -> out = [spk | pot] (2 x 20*200*29*29 fp32)
//
// r22: conv2 sparse walk (36us, VALUBusy 64%, 7 failed restructurings)
// replaced by dense bf16 MFMA implicit GEMM: per (t,ph) block, expand mask1
// bits to bf16 A[col][k] in LDS (k = c*9+kh*3+kw, 272 padded), 8 waves x
// 3 rows x 3 coltiles x 17 v_mfma_f32_32x32x16_bf16 vs frag-linear w2b held
// in VGPRs. Fire+pool3x3 in-register via the verified C/D map; emits the
// UNCHANGED pool2m ballot format -> conv3 identical. 661k MFMAs ~ 2.2us
// matrix-pipe floor; est 10-14us vs 36. bf16 w2 rounding << 0.6 margin to
// threshold 1.0 -> spike set / flags2 / output invariant (absmax stays 0).
// r21: conv1m loads x directly (boundary-guarded); w2 pack in conv1m tail.
// r19: conv1 as bf16 MFMA implicit GEMM.

#define OUT_HALF 3364000  // 20*200*29*29
#define MASK_PLANE 128000 // 20*80*80 (u32 elements per plane)
#define T_FLOATS 168200   // 200*29*29 floats per t per half

typedef float f32x16 __attribute__((ext_vector_type(16)));
typedef short bf8s __attribute__((ext_vector_type(8)));
typedef float f32x4 __attribute__((ext_vector_type(4)));
typedef f32x4 f32x4u __attribute__((aligned(4)));  // 4B-aligned vec4 load

static __device__ __forceinline__ unsigned int pkbf(float a, float b) {
    union { __hip_bfloat162 h; unsigned int u; } cv;
    cv.h = __float22bfloat162_rn(make_float2(a, b));
    return cv.u;
}
static __device__ __forceinline__ unsigned short bfbits(float a) {
    union { __hip_bfloat16 h; unsigned short u; } cv;
    cv.h = __float2bfloat16(a);
    return cv.u;
}

// ---------------- conv1 (bf16 MFMA) + fire(1) + pool2x2 -> mask1
//                  blocks 0..1999: conv1; 2000..2271: w2b pack + flags2 zero
// conv1 block b: t = b/100; wave unit u = (b%100)*4 + wave -> pr = u/5
// (pool row 0..79), jblk = u%5 (32 cols). Per wave: output rows 2pr (acc0),
// 2pr+1 (acc1), cols j0..j0+31, all 32 ocs (30 real + 2 zero).
// A-frag (ks slice = channel ks): lane(m=l&31,hi=l>>5) needs SOURCE rows
// (2pr+2hi-2)+{0,1,2} x cols (j-2)..(j+1); interior lanes use 3 float4
// loads, boundary lanes 12 guarded scalars.
// w2b pack: frag-linear bf16 w2 for conv2's MFMA:
//   w2b[((ocg*17+ks)*64 + l)*8 + i] = bf16(w2[ocg*32+(l&31)][ks*16+(l>>5)*8+i])
//   (zero for oc>=250 or k>=270), k = c*9+kh*3+kw = w2's flat ck order.
// C/D: col(oc)=lane&31, row(j-idx)=(reg&3)+8*(reg>>2)+4*hi  [verified map]
__global__ __launch_bounds__(256) void k_conv1m(const float* __restrict__ x,
                                                const float* __restrict__ w1,
                                                const float* __restrict__ w2,
                                                unsigned short* __restrict__ w2b,
                                                unsigned int* __restrict__ mask1,
                                                unsigned int* __restrict__ flags2) {
    int tid = threadIdx.x;
    if (blockIdx.x >= 2000) {  // w2b pack, 272 blocks x 256 = 69632 elems exact
        int tb = blockIdx.x - 2000;
        if (tb == 0)
            for (int i = tid; i < 540; i += 256) flags2[i] = 0u;
        int idx = tb * 256 + tid;
        int i8 = idx & 7;
        int ll = (idx >> 3) & 63;
        int gi = idx >> 9;                 // [0,136) = ocg*17+ks
        int ocg = (gi * 1928) >> 15;       // /17
        int ks = gi - ocg * 17;
        int oc = ocg * 32 + (ll & 31);
        int k = ks * 16 + ((ll >> 5) << 3) + i8;
        float w = (oc < 250 && k < 270) ? w2[oc * 270 + k] : 0.f;
        w2b[idx] = bfbits(w);
        return;
    }

    __shared__ unsigned short B_lds[6 * 64 * 8];  // 6 KiB, frag-linear

    // stage B fragments: elem (ks, lane ll, i) at q=(ks*64+ll)*8+i
#pragma unroll
    for (int n = 0; n < 12; ++n) {
        int q = n * 256 + tid;
        int i = q & 7, ll = (q >> 3) & 63, ks = q >> 9;
        int oc = ll & 31;
        int kg = ks * 16 + ((ll >> 5) << 3) + i;
        float w = (oc < 30) ? w1[oc * 96 + kg] : 0.f;
        B_lds[q] = bfbits(w);
    }
    __syncthreads();

    int l = tid & 63, wv = tid >> 6;
    int b = blockIdx.x;
    int t = b / 100;
    int u = (b % 100) * 4 + wv;
    int pr = u / 5, jblk = u % 5;
    int m = l & 31, hi = l >> 5;
    int j = jblk * 32 + m;

    bf8s bq[6];
#pragma unroll
    for (int ks = 0; ks < 6; ++ks)
        bq[ks] = *(const bf8s*)&B_lds[(ks * 64 + l) * 8];

    f32x16 acc0 = (f32x16)(0.0f);
    f32x16 acc1 = (f32x16)(0.0f);
    int sr0 = 2 * pr + 2 * hi - 2;  // first SOURCE row needed by this lane
    int sc0 = j - 2;                // first SOURCE col
    bool fast = ((unsigned)sr0 <= 157u) && ((unsigned)sc0 <= 156u);

#pragma unroll
    for (int ks = 0; ks < 6; ++ks) {
        const float* xp = x + (t * 6 + ks) * 25600;
        f32x4 v0, v1, v2;
        if (fast) {
            const float* bp = xp + sr0 * 160 + sc0;
            v0 = *(const f32x4u*)(bp);
            v1 = *(const f32x4u*)(bp + 160);
            v2 = *(const f32x4u*)(bp + 320);
        } else {
            float tmp[3][4];
#pragma unroll
            for (int r = 0; r < 3; ++r)
#pragma unroll
                for (int e = 0; e < 4; ++e) {
                    int sr = sr0 + r, sc = sc0 + e;
                    tmp[r][e] = ((unsigned)sr < 160u && (unsigned)sc < 160u)
                                    ? xp[sr * 160 + sc] : 0.f;
                }
            v0.x = tmp[0][0]; v0.y = tmp[0][1]; v0.z = tmp[0][2]; v0.w = tmp[0][3];
            v1.x = tmp[1][0]; v1.y = tmp[1][1]; v1.z = tmp[1][2]; v1.w = tmp[1][3];
            v2.x = tmp[2][0]; v2.y = tmp[2][1]; v2.z = tmp[2][2]; v2.w = tmp[2][3];
        }
        union { bf8s s; unsigned int u4[4]; } a0, a1;
        a0.u4[0] = pkbf(v0.x, v0.y);
        a0.u4[1] = pkbf(v0.z, v0.w);
        a0.u4[2] = pkbf(v1.x, v1.y);
        a0.u4[3] = pkbf(v1.z, v1.w);
        a1.u4[0] = a0.u4[2];
        a1.u4[1] = a0.u4[3];
        a1.u4[2] = pkbf(v2.x, v2.y);
        a1.u4[3] = pkbf(v2.z, v2.w);
        acc0 = __builtin_amdgcn_mfma_f32_32x32x16_bf16(a0.s, bq[ks], acc0, 0, 0, 0);
        acc1 = __builtin_amdgcn_mfma_f32_32x32x16_bf16(a1.s, bq[ks], acc1, 0, 0, 0);
    }

    // fire(>1) + pool2x2 + pack 30 oc bits -> 3 mask planes of 10 bits
    unsigned int mbase = (unsigned int)((t * 80 + pr) * 80 + jblk * 16);
#pragma unroll
    for (int a = 0; a < 8; ++a) {
        bool s = acc0[2 * a] > 1.f || acc0[2 * a + 1] > 1.f ||
                 acc1[2 * a] > 1.f || acc1[2 * a + 1] > 1.f;
        unsigned long long bal = __ballot(s);
        if (l < 6) {
            int h = l >> 1;
            unsigned int word = (l & 1) ? (unsigned int)(bal >> 32)
                                        : (unsigned int)bal;
            int pc = (a & 1) + ((a >> 1) << 2) + ((l & 1) << 1);
            mask1[h * MASK_PLANE + mbase + pc] = (word >> (10 * h)) & 0x3FFu;
        }
    }
}

// ---------------- conv2 dense bf16 MFMA + fire(1.0) + pool3x3 -> pool2m
// block: (t, ph) = 540 blocks x 512 thr (8 waves = 8 oc-groups of 32).
// Stage 5x84 merged mask band (as before). Per output row r = 3ph+rho:
// build A_lds[col 0..81][k 0..271] bf16 (A[s][k] = spike bit c of
// m_lds[rho+kh][s+kw], k = c*9+kh*3+kw; 164 threads, static unrolled).
// Each wave: 3 coltiles x 17 MFMAs (A from LDS b128, B = 68-VGPR frags from
// w2b). Fire bits via C/D map (col=lane&31 -> oc; reg -> spatial col),
// shfl_xor(32) merges k-halves, OR rows, in-lane 3-col pooling, 27 ballots
// -> pool2m u32 halves in the EXACT old format. Garbage cols 82..95 (stale
// LDS) never reach pooling (pool uses cols 0..80 only).
__global__ __launch_bounds__(512) void k_conv2(const unsigned int* __restrict__ mask1,
                                               const unsigned short* __restrict__ w2b,
                                               unsigned int* __restrict__ pool2m32,
                                               unsigned int* __restrict__ flags2) {
    __shared__ unsigned int m_lds[5 * 84];        // 1680 B
    __shared__ unsigned short A_lds[96 * 280];    // 53760 B, [col][k] stride 280

    int b = blockIdx.x;
    int ph = b % 27, t = b / 27;
    int tid = threadIdx.x;
    int l = tid & 63, wv = tid >> 6;
    int m = l & 31, hi = l >> 5;
    int r0 = 3 * ph - 2;

    // B fragments: 17 x 16B coalesced global loads, live in VGPRs
    bf8s bfr[17];
    {
        const unsigned short* wbp = w2b + (wv * 17 * 64 + l) * 8;
#pragma unroll
        for (int ks = 0; ks < 17; ++ks)
            bfr[ks] = *(const bf8s*)(wbp + ks * 512);
    }

    // stage mask band: pool1 rows r0..r0+4, cols -2..81 (3 planes merged)
    if (tid < 420) {
        int r = tid / 84, col = tid % 84;
        int gr = r0 + r, gc = col - 2;
        unsigned int v = 0;
        if ((unsigned)gr < 80u && (unsigned)gc < 80u) {
            int i2 = (t * 80 + gr) * 80 + gc;
            v = mask1[i2] | (mask1[MASK_PLANE + i2] << 10) |
                (mask1[2 * MASK_PLANE + i2] << 20);
        }
        m_lds[tid] = v;
    }
    __syncthreads();

    unsigned int rowor[3] = {0u, 0u, 0u};  // per coltile: OR over 3 rows

#pragma unroll
    for (int rho = 0; rho < 3; ++rho) {
        if (rho > 0) __syncthreads();  // protect A_lds from overwrite

        // ---- build A_lds for output row 3ph+rho: 164 threads, 2 k-halves
        if (tid < 164) {
            int s = tid >> 1;
            unsigned int w[9];
#pragma unroll
            for (int tp = 0; tp < 9; ++tp)
                w[tp] = m_lds[(rho + tp / 3) * 84 + s + (tp % 3)];
            if ((tid & 1) == 0) {
                unsigned int* dst = (unsigned int*)&A_lds[s * 280];
#pragma unroll
                for (int kp = 0; kp < 68; ++kp) {
                    const int k0 = 2 * kp, k1 = k0 + 1;
                    unsigned int v = 0;
                    { const int c = k0 / 9, tp = k0 % 9;
                      v |= ((w[tp] >> c) & 1u) ? 0x3F80u : 0u; }
                    { const int c = k1 / 9, tp = k1 % 9;
                      v |= ((w[tp] >> c) & 1u) ? 0x3F800000u : 0u; }
                    dst[kp] = v;
                }
            } else {
                unsigned int* dst = (unsigned int*)&A_lds[s * 280 + 136];
#pragma unroll
                for (int kp = 0; kp < 68; ++kp) {
                    const int k0 = 136 + 2 * kp, k1 = k0 + 1;
                    unsigned int v = 0;
                    if (k0 < 270) { const int c = k0 / 9, tp = k0 % 9;
                                    v |= ((w[tp] >> c) & 1u) ? 0x3F80u : 0u; }
                    if (k1 < 270) { const int c = k1 / 9, tp = k1 % 9;
                                    v |= ((w[tp] >> c) & 1u) ? 0x3F800000u : 0u; }
                    dst[kp] = v;
                }
            }
        }
        __syncthreads();

        // ---- compute: 3 coltiles x 17 MFMAs
#pragma unroll
        for (int ct = 0; ct < 3; ++ct) {
            f32x16 acc = (f32x16)(0.0f);
            const unsigned short* ap = &A_lds[(ct * 32 + m) * 280 + hi * 8];
#pragma unroll
            for (int ks = 0; ks < 17; ++ks) {
                bf8s af = *(const bf8s*)(ap + ks * 16);
                acc = __builtin_amdgcn_mfma_f32_32x32x16_bf16(af, bfr[ks], acc, 0, 0, 0);
            }
            unsigned int cm = 0;
#pragma unroll
            for (int a = 0; a < 16; ++a) {
                int col = (a & 3) + 8 * (a >> 2) + 4 * hi;
                cm |= (acc[a] > 1.f) ? (1u << col) : 0u;
            }
            cm |= __shfl_xor(cm, 32);  // merge k-halves: lane ocl <-> ocl+32
            rowor[ct] |= cm;
        }
    }

    // ---- pool3x3 over cols (rows already OR'd): pooled pc uses cols 3pc..3pc+2
    unsigned long long lo = (unsigned long long)rowor[0] |
                            ((unsigned long long)rowor[1] << 32);
    unsigned int mid = (rowor[1] >> 31) | (rowor[2] << 1);  // global bits 63..
    unsigned int pooled = 0;
#pragma unroll
    for (int pc = 0; pc < 21; ++pc)
        pooled |= ((lo >> (3 * pc)) & 7ull) ? (1u << pc) : 0u;
#pragma unroll
    for (int pc = 21; pc < 27; ++pc)
        pooled |= ((mid >> (3 * (pc - 21))) & 7u) ? (1u << pc) : 0u;

    // ---- transpose to per-(pc, ocg) 32-bit oc words via 27 ballots
    unsigned int base = (unsigned int)((t * 27 + ph) * 27) * 8;
    unsigned int orAll = 0;
#pragma unroll
    for (int pc = 0; pc < 27; ++pc) {
        unsigned long long bal = __ballot((pooled >> pc) & 1u);
        unsigned int wrd = (unsigned int)bal;  // lanes 0..31 = ocs of this ocg
        if (l == pc) pool2m32[base + pc * 8 + wv] = wrd;
        orAll |= wrd;
    }
    if (l == 0 && orAll) flags2[t * 27 + ph] = 1u;  // same-value multi-writer
}

// ---------------- conv3(3x3) + fire(25.0) -> out [spk|pot] (20,200,29,29) x2
// block: (t, 5 oc-groups of 40, 15 row-pairs), 320 thr = 40oc x 8 col-tiles(4)
// Fast path: all 27 flags of t clear -> whole t-image zeroed with contiguous
// float4 stores. Row-pair early-out and dense path kept for arbitrary inputs.
__global__ __launch_bounds__(320) void k_conv3(const unsigned long long* __restrict__ pool2m,
                                               const float* __restrict__ w3,
                                               float* __restrict__ out,
                                               const unsigned int* __restrict__ flags2) {
    __shared__ float w_lds[25 * 9 * 40];   // 9000 floats, [ck_local][ocl]
    __shared__ float in_lds[25 * 4 * 34];  // 3400 floats, [cl][r][col]

    int b = blockIdx.x;
    int rb = b % 15;  b /= 15;
    int ocg = b % 5;  b /= 5;
    int t = b;
    int oc0 = ocg * 40;
    int r0 = 2 * rb;  // output rows r0, r0+1
    int tid = threadIdx.x;
    int ocl = tid % 40, ct = tid / 40;  // ct in [0,8)

    // whole-t union of flags (wave-uniform scalar loads)
    {
        unsigned int fT = 0;
        const unsigned int* fp = flags2 + t * 27;
#pragma unroll
        for (int r = 0; r < 27; ++r) fT |= fp[r];
        if (fT == 0) {
            float4 z; z.x = 0.f; z.y = 0.f; z.z = 0.f; z.w = 0.f;
            float4* o0 = (float4*)(out + (size_t)t * T_FLOATS);
            float4* o1 = (float4*)(out + OUT_HALF + (size_t)t * T_FLOATS);
            int s = ocg * 15 + rb;           // slice id 0..74
            int lo = s * 561;                // 75*561 = 42075 >= 42050
            int hi = lo + 561; if (hi > 42050) hi = 42050;
            for (int i = lo + tid; i < hi; i += 320) {
                o0[i] = z;
                o1[i] = z;
            }
            return;
        }
    }

    // receptive field: pool2 rows r0-2..r0+1
    {
        unsigned int f = 0;
        int rlo = r0 - 2; if (rlo < 0) rlo = 0;
        int rhi = r0 + 1; if (rhi > 26) rhi = 26;
        for (int r = rlo; r <= rhi; ++r) f |= flags2[t * 27 + r];
        if (f == 0) {
            int nrows = (r0 + 1 < 29) ? 2 : 1;
            int stride = 29 * nrows;
            int cnt = 40 * stride;
            for (int idx = tid; idx < cnt; idx += 320) {
                int o = idx / stride, rem = idx % stride;
                size_t base = (size_t)((t * 200 + oc0 + o) * 29 + r0) * 29 + rem;
                out[base] = 0.f;
                out[OUT_HALF + base] = 0.f;
            }
            return;
        }
    }

    float acc[2][4];
#pragma unroll
    for (int i = 0; i < 2; ++i)
#pragma unroll
        for (int j = 0; j < 4; ++j) acc[i][j] = 0.f;

    for (int chn = 0; chn < 10; ++chn) {  // channel chunks of 25
        int cc0 = chn * 25;
        for (int idx = tid; idx < 25 * 9 * 40; idx += 320) {
            int o = idx % 40, ck = idx / 40;         // ck in [0,225)
            int ckg = cc0 * 9 + ck;                  // global (c,kh,kw) index
            w_lds[idx] = w3[(size_t)(oc0 + o) * 2250 + ckg];
        }
        for (int idx = tid; idx < 25 * 4 * 34; idx += 320) {
            int col = idx % 34;
            int rem = idx / 34;
            int r = rem & 3, cl = rem >> 2;
            int gr = r0 + r - 2, gc = col - 2;
            float v = 0.f;
            if ((unsigned)gr < 27u && (unsigned)gc < 27u) {
                int c = cc0 + cl;
                unsigned long long wbits =
                    pool2m[((t * 27 + gr) * 27 + gc) * 4 + (c >> 6)];
                v = (float)((wbits >> (c & 63)) & 1ull);
            }
            in_lds[idx] = v;
        }
        __syncthreads();

        for (int cl = 0; cl < 25; ++cl) {
            float in[4][6];
#pragma unroll
            for (int r = 0; r < 4; ++r)
#pragma unroll
                for (int j = 0; j < 6; ++j)
                    in[r][j] = in_lds[(cl * 4 + r) * 34 + ct * 4 + j];
            const float* wp = &w_lds[cl * 360 + ocl];
#pragma unroll
            for (int k = 0; k < 9; ++k) {
                float w = wp[k * 40];
                int kh = k / 3, kw = k % 3;
#pragma unroll
                for (int i = 0; i < 2; ++i)
#pragma unroll
                    for (int j = 0; j < 4; ++j)
                        acc[i][j] += in[i + kh][j + kw] * w;
            }
        }
        __syncthreads();
    }

    {
        int oc = oc0 + ocl;  // always < 200
#pragma unroll
        for (int i = 0; i < 2; ++i) {
            int r = r0 + i;
            if (r < 29) {
#pragma unroll
                for (int j = 0; j < 4; ++j) {
                    int col = ct * 4 + j;
                    if (col < 29) {
                        float pot = acc[i][j];
                        bool s = pot > 25.f;
                        size_t base = ((size_t)((t * 200 + oc) * 29 + r)) * 29 + col;
                        out[base] = s ? 1.f : 0.f;
                        out[OUT_HALF + base] = s ? pot : 0.f;
                    }
                }
            }
        }
    }
}

extern "C" void kernel_launch(void* const* d_in, const int* in_sizes, int n_in,
                              void* d_out, int out_size, void* d_ws, size_t ws_size,
                              hipStream_t stream) {
    const float* x  = (const float*)d_in[0];
    const float* w1 = (const float*)d_in[1];
    const float* w2 = (const float*)d_in[2];
    const float* w3 = (const float*)d_in[3];
    float* out = (float*)d_out;

    // workspace layout (bytes):
    //   mask1  u32: [0, 1,536,000)           3 planes x 20*80*80
    //   pool2m u64: [1,536,000, 2,002,560)   20*27*27*4 x 8B ballot words
    //   w2b   bf16: [2,002,560, 2,141,824)   8x17x64x8 frag-linear conv2 B
    //   flags2    : [2,277,376, +2,160)      u32[20*27]
    unsigned int* mask1 = (unsigned int*)d_ws;
    unsigned long long* pool2m = (unsigned long long*)((char*)d_ws + 1536000);
    unsigned short* w2b = (unsigned short*)((char*)d_ws + 2002560);
    unsigned int* flags2 = (unsigned int*)((char*)d_ws + 2277376);

    // blocks 0..1999: conv1 MFMA; blocks 2000..2271: w2b pack + flags2 zero
    k_conv1m<<<2272, 256, 0, stream>>>(x, w1, w2, w2b, mask1, flags2);
    k_conv2<<<20 * 27, 512, 0, stream>>>(mask1, w2b, (unsigned int*)pool2m, flags2);
    k_conv3<<<20 * 5 * 15, 320, 0, stream>>>(pool2m, w3, out, flags2);
}